// Round 8
// baseline (1235.549 us; speedup 1.0000x reference)
//
#include <hip/hip_runtime.h>
#include <hip/hip_fp16.h>

// LightGCN on MI355X. y-formulation (y = dinv*x, fp16 128B rows):
//   h[d] = dinv[d] * sum_{e in N(d)} y[src_e];  y_next = dinv*h.
// Pipeline: binA (bin edges by dst>>8 into 586 buckets, LDS-staged, fused
// global degree hist) -> prescale (dinv, sqdeg, y0=fp16(emb*dinv)) ->
// 3x LDS-tile bucket gather (block = 128-node half-bucket, fp32 LDS tile,
// sequential bin reads, 8-rows-per-instruction gathers, ds_add accumulate).
// Layer 3 reconstructs h1,h2 from y1,y2 (h = y*sqrt(deg)) and writes
// out = (emb + h1 + h2 + h3)/4.
//
// d_in[0]: edge_index int32 [2][1M]; d_in[1]: emb_weight fp32 [150000][64]
// d_out  : 150000x64 fp32

constexpr int kNodes     = 150000;
constexpr int kDim       = 64;
constexpr int kEdges     = 1000000;
constexpr int kEmbFloats = kNodes * kDim;            // 9,600,000
constexpr int kBkt       = (kNodes + 255) / 256;     // 586 buckets
constexpr int kBktCap    = 2048;                     // mean 1707, +8.3 sigma
constexpr int kChunk     = 4096;                     // edges per binA block
constexpr int kHStride   = 68;                       // LDS tile row stride (bank spread)

__device__ __forceinline__ int wave_incl_scan(int v, int lane) {
    #pragma unroll
    for (int s = 1; s < 64; s <<= 1) {
        int u = __shfl_up(v, s);
        if (lane >= s) v += u;
    }
    return v;
}

// ---------------- binA: bin edges by dst>>8 (LDS-staged) + global deg hist ----

__global__ __launch_bounds__(1024) void binA_kernel(const int* __restrict__ src,
                                                    const int* __restrict__ dst,
                                                    int* __restrict__ cur,      // [kBkt] zeroed
                                                    int* __restrict__ counts,   // [kNodes] zeroed
                                                    unsigned* __restrict__ bin) {
    __shared__ int hist[1024];
    __shared__ int cursor[1024];
    __shared__ int sexcl[1024];
    __shared__ int gstart[1024];
    __shared__ int wsum[16];
    __shared__ unsigned staged[kChunk];
    __shared__ unsigned short sbkt[kChunk];

    int t      = threadIdx.x;
    int lane   = t & 63;
    int w      = t >> 6;
    int chunk0 = blockIdx.x * kChunk;
    int n      = min(kChunk, kEdges - chunk0);

    hist[t] = 0;
    __syncthreads();

    int myb[4], myd[4];
    #pragma unroll
    for (int j = 0; j < 4; ++j) {
        int i = j * 1024 + t;
        if (i < n) {
            int d = dst[chunk0 + i];
            myb[j] = d >> 8;
            myd[j] = d & 255;
            atomicAdd(&hist[myb[j]], 1);
            atomicAdd(&counts[d], 1);          // fused global degree histogram
        } else myb[j] = -1;
    }
    __syncthreads();

    int c   = hist[t];
    int inc = wave_incl_scan(c, lane);
    if (lane == 63) wsum[w] = inc;
    __syncthreads();
    if (w == 0) {
        int v  = (lane < 16) ? wsum[lane] : 0;
        int sc = wave_incl_scan(v, lane);
        if (lane < 16) wsum[lane] = sc - v;
    }
    __syncthreads();
    int excl = wsum[w] + inc - c;
    sexcl[t]  = excl;
    cursor[t] = excl;
    if (t < kBkt) gstart[t] = atomicAdd(&cur[t], c);
    __syncthreads();

    #pragma unroll
    for (int j = 0; j < 4; ++j) {
        int i = j * 1024 + t;
        if (i < n) {
            int s = src[chunk0 + i];
            unsigned pk = ((unsigned)myd[j] << 24) | (unsigned)s;
            int p = atomicAdd(&cursor[myb[j]], 1);
            staged[p] = pk;
            sbkt[p]   = (unsigned short)myb[j];
        }
    }
    __syncthreads();

    #pragma unroll
    for (int j = 0; j < 4; ++j) {
        int i = j * 1024 + t;
        if (i < n) {
            int bu = sbkt[i];
            int gp = gstart[bu] + (i - sexcl[bu]);
            if (gp < kBktCap) bin[(size_t)bu * kBktCap + gp] = staged[i];
        }
    }
}

// ------------- prescale: dinv, sqdeg, y0 = fp16(emb * dinv) -------------
// one thread per 8 dims (int4 of y0).

__global__ __launch_bounds__(256) void prescale_kernel(const int* __restrict__ counts,
                                                       const float4* __restrict__ emb4,
                                                       float* __restrict__ dinv,
                                                       float* __restrict__ sqdeg,
                                                       int4* __restrict__ y4) {
    int i = blockIdx.x * 256 + threadIdx.x;
    if (i >= kEmbFloats / 8) return;
    int node = i >> 3;
    int c = counts[node];
    float dv = (c > 0) ? rsqrtf((float)c) : 0.0f;
    if ((i & 7) == 0) {
        dinv[node]  = dv;
        sqdeg[node] = (c > 0) ? sqrtf((float)c) : 0.0f;
    }
    float4 v0 = emb4[(size_t)i * 2];
    float4 v1 = emb4[(size_t)i * 2 + 1];
    __half2 p0 = __floats2half2_rn(v0.x * dv, v0.y * dv);
    __half2 p1 = __floats2half2_rn(v0.z * dv, v0.w * dv);
    __half2 p2 = __floats2half2_rn(v1.x * dv, v1.y * dv);
    __half2 p3 = __floats2half2_rn(v1.z * dv, v1.w * dv);
    int4 wv;
    wv.x = *reinterpret_cast<int*>(&p0); wv.y = *reinterpret_cast<int*>(&p1);
    wv.z = *reinterpret_cast<int*>(&p2); wv.w = *reinterpret_cast<int*>(&p3);
    y4[i] = wv;
}

// ------------- gather: block = 128-node half-bucket, LDS fp32 tile -------------
// lane = g*8 + q : g = edge slot (8 slots/round), q = int4 chunk (8 dims).
// Reads bucket edges sequentially from bin; accumulates rows into LDS via
// ds_add (stride-68 rows -> 2-way bank aliasing, free).
// mode 0: y[node] = fp16(dinv^2 * h);  mode 1: out = (emb+(y1+y2)*sqdeg+dinv*h)/4.

__global__ __launch_bounds__(256) void gather_kernel(const int* __restrict__ cur,
                                                     const unsigned* __restrict__ bin,
                                                     const __half* __restrict__ x16,
                                                     const float* __restrict__ dinv,
                                                     const float* __restrict__ sqdeg,
                                                     __half* __restrict__ yOut,
                                                     const float4* __restrict__ emb4,
                                                     const __half* __restrict__ y1,
                                                     const __half* __restrict__ y2,
                                                     float4* __restrict__ out4,
                                                     int mode) {
    __shared__ float hbuf[128 * kHStride];           // 34,816 B

    int blk  = blockIdx.x;
    int bkt  = blk >> 1;
    unsigned half = (unsigned)(blk & 1);
    int t    = threadIdx.x;
    int lane = t & 63;
    int w    = t >> 6;                               // 4 waves
    int q    = lane & 7;
    int g    = lane >> 3;

    {   // zero the tile
        float4 z = make_float4(0.f, 0.f, 0.f, 0.f);
        float4* hb4 = (float4*)hbuf;
        for (int i = t; i < 128 * kHStride / 4; i += 256) hb4[i] = z;
    }
    __syncthreads();

    int cnt = min(cur[bkt], kBktCap);
    const unsigned* mybin = bin + (size_t)bkt * kBktCap;

    for (int c0 = w * 64; c0 < cnt; c0 += 256) {
        int m = cnt - c0;
        if (m > 64) m = 64;
        unsigned raw = (lane < m) ? mybin[c0 + lane] : 0u;
        for (int i = 0; i < m; i += 8) {
            int slot = i + g;
            unsigned v = __shfl(raw, slot);
            bool act = (slot < m) && (((v >> 31) & 1u) == half);
            unsigned sidx = act ? (v & 0x00FFFFFFu) : 0u;
            int4 r = ((const int4*)(x16 + (size_t)sidx * kDim))[q];
            if (act) {
                int dl = (int)((v >> 24) & 127u);
                float* hr = &hbuf[dl * kHStride + q * 8];
                float2 f0 = __half22float2(*reinterpret_cast<__half2*>(&r.x));
                float2 f1 = __half22float2(*reinterpret_cast<__half2*>(&r.y));
                float2 f2 = __half22float2(*reinterpret_cast<__half2*>(&r.z));
                float2 f3 = __half22float2(*reinterpret_cast<__half2*>(&r.w));
                atomicAdd(&hr[0], f0.x); atomicAdd(&hr[1], f0.y);
                atomicAdd(&hr[2], f1.x); atomicAdd(&hr[3], f1.y);
                atomicAdd(&hr[4], f2.x); atomicAdd(&hr[5], f2.y);
                atomicAdd(&hr[6], f3.x); atomicAdd(&hr[7], f3.y);
            }
        }
    }
    __syncthreads();

    int n0 = (bkt << 8) + (int)half * 128;

    if (mode == 0) {
        // 128 rows x 8 int4 = 1024 stores
        for (int i = t; i < 128 * 8; i += 256) {
            int dl = i >> 3, qq = i & 7;
            int node = n0 + dl;
            if (node >= kNodes) continue;
            float dv = dinv[node];
            float dv2 = dv * dv;
            const float* hr = &hbuf[dl * kHStride + qq * 8];
            __half2 p0 = __floats2half2_rn(hr[0] * dv2, hr[1] * dv2);
            __half2 p1 = __floats2half2_rn(hr[2] * dv2, hr[3] * dv2);
            __half2 p2 = __floats2half2_rn(hr[4] * dv2, hr[5] * dv2);
            __half2 p3 = __floats2half2_rn(hr[6] * dv2, hr[7] * dv2);
            int4 wv;
            wv.x = *reinterpret_cast<int*>(&p0); wv.y = *reinterpret_cast<int*>(&p1);
            wv.z = *reinterpret_cast<int*>(&p2); wv.w = *reinterpret_cast<int*>(&p3);
            ((int4*)(yOut + (size_t)node * kDim))[qq] = wv;
        }
    } else {
        // 128 rows x 16 float4 = 2048 stores
        for (int i = t; i < 128 * 16; i += 256) {
            int dl = i >> 4, qq = i & 15;
            int node = n0 + dl;
            if (node >= kNodes) continue;
            float dv = dinv[node];
            float sq = sqdeg[node];
            const float* hr = &hbuf[dl * kHStride + qq * 4];
            size_t fi = (size_t)node * 16 + qq;
            float4 e = emb4[fi];
            int2 r1 = ((const int2*)(y1 + (size_t)node * kDim))[qq];
            int2 r2 = ((const int2*)(y2 + (size_t)node * kDim))[qq];
            float2 a0 = __half22float2(*reinterpret_cast<__half2*>(&r1.x));
            float2 a1 = __half22float2(*reinterpret_cast<__half2*>(&r1.y));
            float2 b0 = __half22float2(*reinterpret_cast<__half2*>(&r2.x));
            float2 b1 = __half22float2(*reinterpret_cast<__half2*>(&r2.y));
            float4 o;
            o.x = (e.x + (a0.x + b0.x) * sq + hr[0] * dv) * 0.25f;
            o.y = (e.y + (a0.y + b0.y) * sq + hr[1] * dv) * 0.25f;
            o.z = (e.z + (a1.x + b1.x) * sq + hr[2] * dv) * 0.25f;
            o.w = (e.w + (a1.y + b1.y) * sq + hr[3] * dv) * 0.25f;
            out4[fi] = o;
        }
    }
}

// ---------------- launch ----------------

extern "C" void kernel_launch(void* const* d_in, const int* in_sizes, int n_in,
                              void* d_out, int out_size, void* d_ws, size_t ws_size,
                              hipStream_t stream) {
    const int*   edge  = (const int*)d_in[0];
    const int*   src   = edge;
    const int*   dst   = edge + kEdges;
    const float* emb_w = (const float*)d_in[1];
    float*       out   = (float*)d_out;

    // Workspace layout — all offsets 256-aligned:
    //   cur    : @0          4,096
    //   counts : @4096       600,064
    //   dinv   : @604160     600,064
    //   sqdeg  : @1204224    600,064
    //   bin    : @1804288    4,800,512  (586 * 2048 * 4)
    //   y0     : @6604800    19,200,000
    //   yA     : @25804800   19,200,000
    //   yB     : @45004800   19,200,000   (end ~64.2 MB)
    char*     ws     = (char*)d_ws;
    int*      cur    = (int*)(ws);
    int*      counts = (int*)(ws + 4096);
    float*    dinv   = (float*)(ws + 604160);
    float*    sqdeg  = (float*)(ws + 1204224);
    unsigned* bin    = (unsigned*)(ws + 1804288);
    __half*   y0     = (__half*)(ws + 6604800);
    __half*   yA     = (__half*)(ws + 25804800);
    __half*   yB     = (__half*)(ws + 45004800);

    const int binABlocks   = (kEdges + kChunk - 1) / kChunk;   // 245
    const int prescaleBlks = (kEmbFloats / 8 + 255) / 256;     // 4688
    const int gatherBlocks = 2 * kBkt;                         // 1172 half-buckets

    hipMemsetAsync(cur, 0, (size_t)kBkt * 4, stream);
    hipMemsetAsync(counts, 0, (size_t)kNodes * 4, stream);
    binA_kernel<<<binABlocks, 1024, 0, stream>>>(src, dst, cur, counts, bin);
    prescale_kernel<<<prescaleBlks, 256, 0, stream>>>(counts, (const float4*)emb_w,
                                                      dinv, sqdeg, (int4*)y0);

    // Layer 1: yA = fp16(dinv^2 * sum y0[src])
    gather_kernel<<<gatherBlocks, 256, 0, stream>>>(cur, bin, y0, dinv, sqdeg,
                                                    yA, nullptr, nullptr, nullptr,
                                                    nullptr, 0);
    // Layer 2: yB = fp16(dinv^2 * sum yA[src])
    gather_kernel<<<gatherBlocks, 256, 0, stream>>>(cur, bin, yA, dinv, sqdeg,
                                                    yB, nullptr, nullptr, nullptr,
                                                    nullptr, 0);
    // Layer 3: out = (emb + h1 + h2 + h3)/4
    gather_kernel<<<gatherBlocks, 256, 0, stream>>>(cur, bin, yB, dinv, sqdeg,
                                                    nullptr, (const float4*)emb_w,
                                                    yA, yB, (float4*)out, 1);
}